// Round 5
// baseline (511.302 us; speedup 1.0000x reference)
//
#include <hip/hip_runtime.h>

#define HH 128
#define RNUM 8
#define CC 40
#define CAP 64                // padded edge slots per dst (P(deg>64) ~ 1e-19)
#define LDA 136               // LDS row stride (bf16): 128 + 8 pad
#define SRCMASK 0x7FFFFFF
#define DEGSTR 16             // deg counter stride in ints: 1 counter per 64-B line

typedef __attribute__((ext_vector_type(8))) short short8;
typedef __attribute__((ext_vector_type(4))) float floatx4;

__device__ __forceinline__ float u2f(unsigned u) {
    union { unsigned u; float f; } c;
    c.u = u;
    return c.f;
}
__device__ __forceinline__ unsigned short f2bf(float f) {
    union { float f; unsigned u; } c;
    c.f = f;
    return (unsigned short)((c.u + 0x7FFFu + ((c.u >> 16) & 1u)) >> 16);
}

// ---------------- edge bucketing: elist[d*64+p] = (rel<<27)|src ----------------
__global__ void fill_kernel(const int* __restrict__ src, const int* __restrict__ dst,
                            const int* __restrict__ et, int* __restrict__ deg,
                            int* __restrict__ elist, int E) {
    int e = blockIdx.x * blockDim.x + threadIdx.x;
    if (e < E) {
        int d = dst[e];
        int p = atomicAdd(&deg[(size_t)d * DEGSTR], 1);
        if (p < CAP) elist[(size_t)d * CAP + p] = (int)(((unsigned)et[e] << 27) | (unsigned)src[e]);
    }
}

// ---------------- Bt[c][n][k] = bf16(Bc[k][n]), c0=root2, c1..8=W2[r] ----------------
__global__ void tcast_kernel(const float* __restrict__ root2, const float* __restrict__ W2,
                             unsigned short* __restrict__ Bt) {
    int bid = blockIdx.x;
    int c = bid >> 5;
    int id = (bid & 31) * 256 + threadIdx.x;
    int n = id >> 6, kp = id & 63;
    const float* B = (c == 0) ? root2 : W2 + (size_t)(c - 1) * HH * HH;
    float g0 = B[(2 * kp) * HH + n];
    float g1 = B[(2 * kp + 1) * HH + n];
    unsigned v = (unsigned)f2bf(g0) | ((unsigned)f2bf(g1) << 16);
    *(unsigned*)(Bt + (size_t)c * HH * HH + n * HH + 2 * kp) = v;
}

// ---------------- layer 1: wave per (dst, channel-half); fp32 W1 gather ----------------
// h[d] = relu( sum_r (1/c_r) * sum_{e in (d,r)} W1[r, src_e] + root1[d] + b1 )
// Channel-split: each wave covers 64 of 128 channels -> 2x waves, 2x TLP, half the VGPRs.
__global__ void gather1_kernel(const int* __restrict__ deg, const int* __restrict__ elist,
                               const float* __restrict__ W1, const float* __restrict__ root1,
                               const float* __restrict__ b1, unsigned short* __restrict__ hbf,
                               int Nn) {
    int gw = (blockIdx.x * blockDim.x + threadIdx.x) >> 6;
    int w = gw >> 1;
    if (w >= Nn) return;
    int half = gw & 1;
    int lane = threadIdx.x & 63;
    int qid = lane >> 4, cl = lane & 15;      // quad gathers one 256 B half-row (16 x float4)
    int dd = min(deg[(size_t)w * DEGSTR], CAP);
    int pk = elist[(size_t)w * CAP + lane];   // one coalesced 256 B load: slot per lane
    int myrel = (lane < dd) ? (int)((unsigned)pk >> 27) : 8;

    // per-relation counts via ballot; lane r holds 1/max(1,c_r)
    float myinv = 1.0f;
#pragma unroll
    for (int r = 0; r < 8; ++r) {
        unsigned long long m = __ballot(myrel == r);
        int c = __popcll(m);
        if (lane == r) myinv = 1.0f / fmaxf(1.0f, (float)c);
    }

    float s0[4] = {0.f, 0.f, 0.f, 0.f};
    float s1[4] = {0.f, 0.f, 0.f, 0.f};
    float s2[4] = {0.f, 0.f, 0.f, 0.f};
    float s3[4] = {0.f, 0.f, 0.f, 0.f};

#define GRP(G, S)                                                                 \
    {                                                                             \
        int j = ((G) << 2) + qid;                                                 \
        int jj = min(j, dd - 1);                                                  \
        int pkj = __shfl(pk, jj);                                                 \
        int rr = (int)((unsigned)pkj >> 27);                                      \
        float wt = __shfl(myinv, rr);                                             \
        int ss = pkj & SRCMASK;                                                   \
        const float* p = W1 + ((size_t)rr * Nn + ss) * HH + half * 64 + cl * 4;   \
        if (j < dd) {                                                             \
            float4 v0 = *(const float4*)p;                                        \
            S[0] += v0.x * wt; S[1] += v0.y * wt; S[2] += v0.z * wt; S[3] += v0.w * wt; \
        }                                                                         \
    }

    int ng = (dd + 3) >> 2;                   // number of 4-edge groups (uniform)
    int g = 0;
    for (; g + 3 < ng; g += 4) {              // 4 streams -> 4 loads in flight/lane
        GRP(g, s0);
        GRP(g + 1, s1);
        GRP(g + 2, s2);
        GRP(g + 3, s3);
    }
    for (; g < ng; ++g) GRP(g, s0);
#undef GRP

#pragma unroll
    for (int k = 0; k < 4; ++k) {
        s0[k] += s1[k] + s2[k] + s3[k];
        s0[k] += __shfl_xor(s0[k], 16);
        s0[k] += __shfl_xor(s0[k], 32);
    }

    if (qid == 0) {
        const float* rp = root1 + (size_t)w * HH + half * 64 + cl * 4;
        float4 r0 = *(const float4*)rp;
        float4 c0 = *(const float4*)(b1 + half * 64 + cl * 4);
        float o[4];
        o[0] = fmaxf(s0[0] + r0.x + c0.x, 0.f);
        o[1] = fmaxf(s0[1] + r0.y + c0.y, 0.f);
        o[2] = fmaxf(s0[2] + r0.z + c0.z, 0.f);
        o[3] = fmaxf(s0[3] + r0.w + c0.w, 0.f);
        ushort4 pk0;
        pk0.x = f2bf(o[0]); pk0.y = f2bf(o[1]); pk0.z = f2bf(o[2]); pk0.w = f2bf(o[3]);
        *(ushort4*)(hbf + (size_t)w * HH + half * 64 + cl * 4) = pk0;
    }
}

// ---------------- dense transform: xrb[c][n][:] = bf16( h[n] @ Bc ), c=0..8 ----------------
// grid = nmb * 9 blocks; block = (m-tile of 64 rows, one c)
__global__ __launch_bounds__(256, 3) void gemmxr_kernel(
    const unsigned short* __restrict__ hbf, const unsigned short* __restrict__ Bt,
    unsigned short* __restrict__ xrb, int Nn, int nmb) {
    __shared__ unsigned short As[64 * LDA];
    __shared__ unsigned short Bs[128 * LDA];
    const int tid = threadIdx.x;
    const int lane = tid & 63, wv = tid >> 6;          // 4 waves
    const int quad = lane >> 4, l16 = lane & 15;
    const int mr = wv & 1, nc = wv >> 1;               // 2x2 wave tiling
    const int mb = blockIdx.x % nmb;
    const int c = blockIdx.x / nmb;
    const int m0 = mb * 64;

    // stage A tile (64 x 128 bf16) once
#pragma unroll
    for (int it = 0; it < 4; ++it) {
        int id = tid + it * 256;
        int rw = id >> 4, c8 = id & 15;
        uint4 v = make_uint4(0, 0, 0, 0);
        if (m0 + rw < Nn) v = *(const uint4*)(hbf + (size_t)(m0 + rw) * HH + c8 * 8);
        *(uint4*)(As + rw * LDA + c8 * 8) = v;
    }
    // stage B (128 x 128 bf16)
    const unsigned short* Bsrc = Bt + (size_t)c * HH * HH;
#pragma unroll
    for (int it = 0; it < 8; ++it) {
        int id = tid + it * 256;
        int rw = id >> 4, c8 = id & 15;
        *(uint4*)(Bs + rw * LDA + c8 * 8) = *(const uint4*)(Bsrc + rw * HH + c8 * 8);
    }
    __syncthreads();

    floatx4 acc[2][4];
#pragma unroll
    for (int a = 0; a < 2; ++a)
#pragma unroll
        for (int bb = 0; bb < 4; ++bb) acc[a][bb] = (floatx4){0.f, 0.f, 0.f, 0.f};

#pragma unroll
    for (int ks = 0; ks < 4; ++ks) {
        short8 a0 = *(const short8*)(As + (mr * 32 + l16) * LDA + ks * 32 + quad * 8);
        short8 a1 = *(const short8*)(As + (mr * 32 + 16 + l16) * LDA + ks * 32 + quad * 8);
#pragma unroll
        for (int nf = 0; nf < 4; ++nf) {
            short8 b = *(const short8*)(Bs + (nc * 64 + nf * 16 + l16) * LDA + ks * 32 + quad * 8);
            acc[0][nf] = __builtin_amdgcn_mfma_f32_16x16x32_bf16(a0, b, acc[0][nf], 0, 0, 0);
            acc[1][nf] = __builtin_amdgcn_mfma_f32_16x16x32_bf16(a1, b, acc[1][nf], 0, 0, 0);
        }
    }

    // pack acc -> Bs rows 0..63 (Bs free now), then coalesced store
    __syncthreads();
#pragma unroll
    for (int mf = 0; mf < 2; ++mf)
#pragma unroll
        for (int nf = 0; nf < 4; ++nf) {
            int gcol = nc * 64 + nf * 16 + l16;
#pragma unroll
            for (int rg = 0; rg < 4; ++rg) {
                int row = mr * 32 + mf * 16 + quad * 4 + rg;
                Bs[row * LDA + gcol] = f2bf(acc[mf][nf][rg]);
            }
        }
    __syncthreads();
#pragma unroll
    for (int it = 0; it < 4; ++it) {
        int id = tid + it * 256;
        int rw = id >> 4, c8 = id & 15;
        if (m0 + rw < Nn)
            *(uint4*)(xrb + ((size_t)c * Nn + m0 + rw) * HH + c8 * 8) =
                *(const uint4*)(Bs + rw * LDA + c8 * 8);
    }
}

// ---------------- layer 2: wave per (dst, channel-half); bf16 xr gather ----------------
// h2[d] = relu( sum_r (1/c_r) sum_{e in (d,r)} xr[rel+1][src_e] + xr[0][d] + b2 )
__global__ void gather2_kernel(const int* __restrict__ deg, const int* __restrict__ elist,
                               const unsigned short* __restrict__ xrb, const float* __restrict__ b2,
                               unsigned short* __restrict__ h2bf, int Nn) {
    int gw = (blockIdx.x * blockDim.x + threadIdx.x) >> 6;
    int d = gw >> 1;
    if (d >= Nn) return;
    int half = gw & 1;
    int lane = threadIdx.x & 63;
    int qid = lane >> 4, cl = lane & 15;      // quad gathers one 128 B bf16 half-row
    int dd = min(deg[(size_t)d * DEGSTR], CAP);
    int pk = elist[(size_t)d * CAP + lane];
    int myrel = (lane < dd) ? (int)((unsigned)pk >> 27) : 8;

    float myinv = 1.0f;
#pragma unroll
    for (int r = 0; r < 8; ++r) {
        unsigned long long m = __ballot(myrel == r);
        int c = __popcll(m);
        if (lane == r) myinv = 1.0f / fmaxf(1.0f, (float)c);
    }

    float s0[4] = {0.f, 0.f, 0.f, 0.f};
    float s1[4] = {0.f, 0.f, 0.f, 0.f};
    float s2[4] = {0.f, 0.f, 0.f, 0.f};
    float s3[4] = {0.f, 0.f, 0.f, 0.f};

#define GRP(G, S)                                                                    \
    {                                                                                \
        int j = ((G) << 2) + qid;                                                    \
        int jj = min(j, dd - 1);                                                     \
        int pkj = __shfl(pk, jj);                                                    \
        int rr = (int)((unsigned)pkj >> 27);                                         \
        float wt = __shfl(myinv, rr);                                                \
        int ss = pkj & SRCMASK;                                                      \
        const unsigned short* p = xrb + ((size_t)(rr + 1) * Nn + ss) * HH + half * 64 + cl * 4; \
        if (j < dd) {                                                                \
            uint2 v = *(const uint2*)p;                                              \
            S[0] += u2f(v.x << 16) * wt; S[1] += u2f(v.x & 0xFFFF0000u) * wt;        \
            S[2] += u2f(v.y << 16) * wt; S[3] += u2f(v.y & 0xFFFF0000u) * wt;        \
        }                                                                            \
    }

    int ng = (dd + 3) >> 2;
    int g = 0;
    for (; g + 3 < ng; g += 4) {
        GRP(g, s0);
        GRP(g + 1, s1);
        GRP(g + 2, s2);
        GRP(g + 3, s3);
    }
    for (; g < ng; ++g) GRP(g, s0);
#undef GRP

#pragma unroll
    for (int k = 0; k < 4; ++k) {
        s0[k] += s1[k] + s2[k] + s3[k];
        s0[k] += __shfl_xor(s0[k], 16);
        s0[k] += __shfl_xor(s0[k], 32);
    }

    if (qid == 0) {
        // self term xr[0][d] (bf16) + b2 (fp32)
        uint2 sv = *(const uint2*)(xrb + (size_t)d * HH + half * 64 + cl * 4);
        float4 c0 = *(const float4*)(b2 + half * 64 + cl * 4);
        float o[4];
        o[0] = fmaxf(s0[0] + u2f(sv.x << 16) + c0.x, 0.f);
        o[1] = fmaxf(s0[1] + u2f(sv.x & 0xFFFF0000u) + c0.y, 0.f);
        o[2] = fmaxf(s0[2] + u2f(sv.y << 16) + c0.z, 0.f);
        o[3] = fmaxf(s0[3] + u2f(sv.y & 0xFFFF0000u) + c0.w, 0.f);
        ushort4 p0;
        p0.x = f2bf(o[0]); p0.y = f2bf(o[1]); p0.z = f2bf(o[2]); p0.w = f2bf(o[3]);
        *(ushort4*)(h2bf + (size_t)d * HH + half * 64 + cl * 4) = p0;
    }
}

// ---------------- final linear: out = h2 @ lin_w + lin_b ----------------
__global__ __launch_bounds__(256, 4) void linout_kernel(
    const unsigned short* __restrict__ h2, const float* __restrict__ lin_w,
    const float* __restrict__ lin_b, float* __restrict__ out, int Nn) {
    __shared__ unsigned short As[64 * LDA];
    __shared__ unsigned short Bs[48 * LDA];
    const int tid = threadIdx.x;
    const int lane = tid & 63, wv = tid >> 6;
    const int quad = lane >> 4, l16 = lane & 15;
    const int m0 = blockIdx.x * 64;

#pragma unroll
    for (int it = 0; it < 4; ++it) {
        int id = tid + it * 256;
        int rw = id >> 4, c8 = id & 15;
        uint4 v = make_uint4(0, 0, 0, 0);
        if (m0 + rw < Nn) v = *(const uint4*)(h2 + (size_t)(m0 + rw) * HH + c8 * 8);
        *(uint4*)(As + rw * LDA + c8 * 8) = v;
    }
    // stage lin_w^T (bf16) rows 0..47 (rows >= CC zeroed)
#pragma unroll
    for (int it = 0; it < 24; ++it) {
        int id = tid + it * 256;
        int n = id >> 7, k = id & 127;
        Bs[n * LDA + k] = (n < CC) ? f2bf(lin_w[(size_t)k * CC + n]) : (unsigned short)0;
    }
    __syncthreads();

    floatx4 acc2[3];
#pragma unroll
    for (int nf = 0; nf < 3; ++nf) acc2[nf] = (floatx4){0.f, 0.f, 0.f, 0.f};
#pragma unroll
    for (int ks = 0; ks < 4; ++ks) {
        short8 a = *(const short8*)(As + (wv * 16 + l16) * LDA + ks * 32 + quad * 8);
#pragma unroll
        for (int nf = 0; nf < 3; ++nf) {
            short8 b = *(const short8*)(Bs + (nf * 16 + l16) * LDA + ks * 32 + quad * 8);
            acc2[nf] = __builtin_amdgcn_mfma_f32_16x16x32_bf16(a, b, acc2[nf], 0, 0, 0);
        }
    }
#pragma unroll
    for (int nf = 0; nf < 3; ++nf) {
        int col = nf * 16 + l16;
        if (col < CC) {
            float lb = lin_b[col];
#pragma unroll
            for (int rg = 0; rg < 4; ++rg) {
                int grow = m0 + wv * 16 + quad * 4 + rg;
                if (grow < Nn) out[(size_t)grow * CC + col] = acc2[nf][rg] + lb;
            }
        }
    }
}

// ---------------- launcher ----------------

extern "C" void kernel_launch(void* const* d_in, const int* in_sizes, int n_in,
                              void* d_out, int out_size, void* d_ws, size_t ws_size,
                              hipStream_t stream) {
    const int* ei      = (const int*)d_in[0];
    const int* et      = (const int*)d_in[1];
    const float* W1    = (const float*)d_in[2];
    const float* root1 = (const float*)d_in[3];
    const float* b1    = (const float*)d_in[4];
    const float* W2    = (const float*)d_in[5];
    const float* root2 = (const float*)d_in[6];
    const float* b2    = (const float*)d_in[7];
    const float* lw    = (const float*)d_in[8];
    const float* lb    = (const float*)d_in[9];
    float* out = (float*)d_out;

    const int E = in_sizes[1];
    const int N = in_sizes[3] / HH;

    // ws: deg[N*16] | elist[N*CAP] ints; then hbf | Bt | xrb[9*N*H] | h2 (bf16)
    int* deg   = (int*)d_ws;
    int* elist = deg + (size_t)N * DEGSTR;
    size_t iofs = (size_t)N * DEGSTR + (size_t)N * CAP;
    iofs = (iofs + 3) & ~(size_t)3;                     // 16B align
    unsigned short* hbf  = (unsigned short*)((int*)d_ws + iofs);
    unsigned short* Bt   = hbf + (size_t)N * HH;
    unsigned short* xrb  = Bt + (size_t)9 * HH * HH;
    unsigned short* h2bf = xrb + (size_t)9 * N * HH;

    const int* src = ei;
    const int* dst = ei + E;

    const int nmb = (N + 63) / 64;

    hipMemsetAsync(deg, 0, (size_t)N * DEGSTR * sizeof(int), stream);
    fill_kernel<<<(E + 255) / 256, 256, 0, stream>>>(src, dst, et, deg, elist, E);
    tcast_kernel<<<9 * 32, 256, 0, stream>>>(root2, W2, Bt);
    gather1_kernel<<<(N * 2 * 64 + 255) / 256, 256, 0, stream>>>(deg, elist, W1, root1, b1, hbf, N);
    gemmxr_kernel<<<nmb * 9, 256, 0, stream>>>(hbf, Bt, xrb, N, nmb);
    gather2_kernel<<<(N * 2 * 64 + 255) / 256, 256, 0, stream>>>(deg, elist, xrb, b2, h2bf, N);
    linout_kernel<<<nmb, 256, 0, stream>>>(h2bf, lw, lb, out, N);
}